// Round 9
// baseline (139.040 us; speedup 1.0000x reference)
//
#include <hip/hip_runtime.h>
#include <hip/hip_bf16.h>

// SelfAttentionLayer: B=64, N=1024, C=128, D=64
// R8: K/V stored fp8-e4m3 in workspace (halves attn's 512 MB L2 stream ->
// 256 MB, the binding resource), upconverted in-register to bf16 at use
// (lossless: fp8 subset of bf16; 8 VALU/frag on the idle pipe). All MFMAs
// remain bf16 -> P stays bf16 (2^25 range, no fp8 overflow issue).
// Structure otherwise = R7 (barrier-free attn, frag-major layouts,
// compile-time ping-pong, LDS-transposed coalesced qkv stores).

#define Bsz 64
#define Nsz 1024
#define Csz 128
#define Dsz 64

typedef __attribute__((ext_vector_type(8))) short short8;
typedef __attribute__((ext_vector_type(4))) float f32x4;
typedef __attribute__((ext_vector_type(2))) float f32x2;

__device__ __forceinline__ unsigned short f2bf(float f) {
    union { float f; unsigned u; } v; v.f = f;
    unsigned r = v.u + 0x7FFF + ((v.u >> 16) & 1);
    return (unsigned short)(r >> 16);
}
__device__ __forceinline__ float bf2f(unsigned short h) {
    union { unsigned u; float f; } v; v.u = ((unsigned)h) << 16;
    return v.f;
}
// pack two fp32 -> bf16x2 dword (round-nearest ties-up; exact on exact vals)
__device__ __forceinline__ unsigned pack_bf16rn(float lo, float hi) {
    unsigned ulo = __float_as_uint(lo) + 0x8000u;
    unsigned uhi = __float_as_uint(hi) + 0x8000u;
    return __builtin_amdgcn_perm(uhi, ulo, 0x07060302u);
}
// 8 x fp8(e4m3) -> 8 x bf16 frag (lossless upconvert, 8 VALU)
__device__ __forceinline__ short8 fp8_to_bf16_frag(uint2 v) {
    f32x2 a = __builtin_amdgcn_cvt_pk_f32_fp8((int)v.x, false);
    f32x2 b = __builtin_amdgcn_cvt_pk_f32_fp8((int)v.x, true);
    f32x2 c = __builtin_amdgcn_cvt_pk_f32_fp8((int)v.y, false);
    f32x2 d = __builtin_amdgcn_cvt_pk_f32_fp8((int)v.y, true);
    union { uint4 u; short8 s; } cv;
    cv.u.x = pack_bf16rn(a[0], a[1]);
    cv.u.y = pack_bf16rn(b[0], b[1]);
    cv.u.z = pack_bf16rn(c[0], c[1]);
    cv.u.w = pack_bf16rn(d[0], d[1]);
    return cv.s;
}
// 8 x bf16 -> 8 x fp8(e4m3) packed (for qkv K/V stores)
__device__ __forceinline__ uint2 bf16x8_to_fp8(short8 v) {
    int lo = __builtin_amdgcn_cvt_pk_fp8_f32(
        bf2f((unsigned short)v[0]), bf2f((unsigned short)v[1]), 0, false);
    lo = __builtin_amdgcn_cvt_pk_fp8_f32(
        bf2f((unsigned short)v[2]), bf2f((unsigned short)v[3]), lo, true);
    int hi = __builtin_amdgcn_cvt_pk_fp8_f32(
        bf2f((unsigned short)v[4]), bf2f((unsigned short)v[5]), 0, false);
    hi = __builtin_amdgcn_cvt_pk_fp8_f32(
        bf2f((unsigned short)v[6]), bf2f((unsigned short)v[7]), hi, true);
    return make_uint2((unsigned)lo, (unsigned)hi);
}

#define SCq (0.125f * 1.44269504f)     // 1/sqrt(D) * log2(e) folded into qs
#define INV_SC (1.0f / (0.125f * 1.44269504f))

// ---------------- Kernel 0: weight prep -> B-frag layout bf16 ----------------
__global__ __launch_bounds__(256) void wprep_kernel(
    const float* __restrict__ Wq, const float* __restrict__ Wk,
    const float* __restrict__ Wv, unsigned short* __restrict__ wfrag)
{
    int t = blockIdx.x * 256 + threadIdx.x;   // 0..1023 = (dt,ksi,lane)
    int lane = t & 63, ksi = (t >> 6) & 3, dt = t >> 8;
    int l16 = lane & 15, quad = lane >> 4;
    int d = dt * 16 + l16;
    int c0 = ksi * 32 + quad * 8;
    short8 q8, k8, v8;
    #pragma unroll
    for (int j = 0; j < 8; j++) {
        q8[j] = (short)f2bf(Wq[(c0 + j) * Dsz + d]);
        k8[j] = (short)f2bf(Wk[(c0 + j) * Dsz + d]);
        v8[j] = (short)f2bf(Wv[(c0 + j) * Dsz + d]);
    }
    int idx = (dt * 4 + ksi) * 64 + lane;
    ((short8*)wfrag)[0 * 1024 + idx] = q8;
    ((short8*)wfrag)[1 * 1024 + idx] = k8;
    ((short8*)wfrag)[2 * 1024 + idx] = v8;
}

// ---------------- Kernel A: QKV projection via MFMA ----------------
// grid 1024 x 256; block = 64 rows; wave = d-tile dt. K/V stored fp8.
__global__ __launch_bounds__(256) void qkv_kernel(
    const float* __restrict__ x, const unsigned short* __restrict__ wfrag,
    const float* __restrict__ bq, const float* __restrict__ bk,
    const float* __restrict__ bv,
    unsigned short* __restrict__ qs, unsigned int* __restrict__ ks2,
    unsigned int* __restrict__ vt2)
{
    __shared__ short lds[16384];          // 32 KB: xh (16 KB) | transpose bufs
    short* xh = lds;
    const int t    = threadIdx.x;
    const int lane = t & 63;
    const int l16  = lane & 15, quad = lane >> 4;
    const int dt   = t >> 6;
    const long rowbase = (long)blockIdx.x * 64;
    const int d = dt * 16 + l16;

    // weight B-frags: 12 coalesced b128 loads (L2-hot wfrag)
    short8 wqf[4], wkf[4], wvf[4];
    #pragma unroll
    for (int ksi = 0; ksi < 4; ksi++) {
        int idx = (dt * 4 + ksi) * 64 + lane;
        wqf[ksi] = ((const short8*)wfrag)[0 * 1024 + idx];
        wkf[ksi] = ((const short8*)wfrag)[1 * 1024 + idx];
        wvf[ksi] = ((const short8*)wfrag)[2 * 1024 + idx];
    }

    // stage x -> bf16 in A-frag layout (v_perm packs)
    {
        const int row = t & 63;
        const float* xrow = x + (rowbase + row) * Csz;
        #pragma unroll
        for (int p = 0; p < 4; p++) {
            int cb = (t >> 6) + p * 4;
            float4 a  = *(const float4*)(xrow + cb * 8);
            float4 bb = *(const float4*)(xrow + cb * 8 + 4);
            uint4 hi4;
            hi4.x = pack_bf16rn(a.x,  a.y);
            hi4.y = pack_bf16rn(a.z,  a.w);
            hi4.z = pack_bf16rn(bb.x, bb.y);
            hi4.w = pack_bf16rn(bb.z, bb.w);
            int unit = ((row >> 4) * 4 + (cb >> 2)) * 64 + ((row & 15) | ((cb & 3) << 4));
            *(uint4*)&xh[unit * 8] = hi4;
        }
    }
    __syncthreads();

    f32x4 aq[4], ak[4], av[4];
    #pragma unroll
    for (int i = 0; i < 4; i++) {
        aq[i] = (f32x4){0.f, 0.f, 0.f, 0.f};
        ak[i] = (f32x4){0.f, 0.f, 0.f, 0.f};
        av[i] = (f32x4){0.f, 0.f, 0.f, 0.f};
    }
    #pragma unroll
    for (int ksi = 0; ksi < 4; ksi++) {
        #pragma unroll
        for (int rt = 0; rt < 4; rt++) {
            short8 ah = *(const short8*)&xh[((rt * 4 + ksi) * 64 + lane) * 8];
            aq[rt] = __builtin_amdgcn_mfma_f32_16x16x32_bf16(ah, wqf[ksi], aq[rt], 0, 0, 0);
            ak[rt] = __builtin_amdgcn_mfma_f32_16x16x32_bf16(ah, wkf[ksi], ak[rt], 0, 0, 0);
            av[rt] = __builtin_amdgcn_mfma_f32_16x16x32_bf16(ah, wvf[ksi], av[rt], 0, 0, 0);
        }
    }

    // ---- epilogue: bias+relu -> LDS transpose -> coalesced stores ----
    const float bqd = bq[d], bkd = bk[d], bvd = bv[d];
    const long b  = rowbase >> 10;
    const int  kt = (int)((rowbase >> 6) & 15);

    __syncthreads();                      // xh reads all done; reuse buffer
    short* stq = lds;                     // [64][72] bf16
    short* stk = lds + 4608;              // [64][72] bf16
    short* stv = lds + 9216;              // [512][8] bf16 V frag image

    float vv[4][4];
    #pragma unroll
    for (int rt = 0; rt < 4; rt++) {
        #pragma unroll
        for (int r = 0; r < 4; r++) {
            int nl = rt * 16 + quad * 4 + r;
            float q = fmaxf(aq[rt][r] + bqd, 0.f);
            float k = fmaxf(ak[rt][r] + bkd, 0.f);
            vv[r][rt] = fmaxf(av[rt][r] + bvd, 0.f);
            stq[nl * 72 + d] = (short)f2bf(q * SCq);
            stk[nl * 72 + d] = (short)f2bf(k);
        }
    }
    #pragma unroll
    for (int r = 0; r < 4; r++) {
        int slot = (dt * 2 + (quad >> 1)) * 64 + (((quad & 1) << 1) | (r >> 1)) * 16 + l16;
        uint2 pk = make_uint2(pack_bf16rn(vv[r][0], vv[r][1]),
                              pack_bf16rn(vv[r][2], vv[r][3]));
        *(uint2*)&stv[slot * 8 + (r & 1) * 4] = pk;
    }
    __syncthreads();

    const long tbase = (long)(b * 16 + kt) * 512;
    #pragma unroll
    for (int i = 0; i < 2; i++) {
        int sidx = i * 256 + t;
        int row = sidx >> 3, g = sidx & 7;
        short8 vq = *(const short8*)&stq[row * 72 + g * 8];
        ((short8*)qs)[(rowbase + row) * 8 + g] = vq;
        int kb = sidx >> 7, rem = sidx & 127, half = rem >> 6, lam = rem & 63;
        short8 vk = *(const short8*)&stk[(kb * 16 + (lam & 15)) * 72 + half * 32 + (lam >> 4) * 8];
        ((uint2*)ks2)[tbase + kb * 128 + half * 64 + lam] = bf16x8_to_fp8(vk);
        short8 v8 = *(const short8*)&stv[sidx * 8];
        ((uint2*)vt2)[tbase + sidx] = bf16x8_to_fp8(v8);
    }
}

// ---------------- Kernel B: barrier-free flash attention ----------------
// grid 512 x 256: b = blk&63 (XCD affinity), qh = blk>>6. 4 waves x 32 q.
// K/V frag loads are b64 fp8 (halved L2 traffic), upconverted at use.
__global__ __launch_bounds__(256) void attn_kernel(
    const unsigned short* __restrict__ qs,
    const unsigned int* __restrict__ ks2,
    const unsigned int* __restrict__ vt2,
    float* __restrict__ out)
{
    __shared__ short Pl[4][32][72];    // per-wave P round-trip + epilogue reuse

    const int t    = threadIdx.x;
    const int wave = t >> 6;
    const int lane = t & 63;
    const int l16  = lane & 15;
    const int quad = lane >> 4;
    const int b    = blockIdx.x & 63;
    const int qh   = blockIdx.x >> 6;
    const int qbase = qh * 128 + wave * 32;

    const uint2* ks8 = (const uint2*)ks2 + (long)b * 8192;
    const uint2* vt8 = (const uint2*)vt2 + (long)b * 8192;

    short8 aq[2][2];
    #pragma unroll
    for (int s = 0; s < 2; s++) {
        const unsigned short* qp = qs + ((long)b * Nsz + qbase + s * 16 + l16) * Dsz + quad * 8;
        aq[s][0] = *(const short8*)(qp);
        aq[s][1] = *(const short8*)(qp + 32);
    }

    f32x4 O[2][4];
    float lsum[2][4];
    #pragma unroll
    for (int s = 0; s < 2; s++)
        #pragma unroll
        for (int i = 0; i < 4; i++) { O[s][i] = (f32x4){0.f,0.f,0.f,0.f}; lsum[s][i] = 0.f; }

    uint2 kfA[4][2], kfB[4][2];
    #pragma unroll
    for (int kb = 0; kb < 4; kb++) {
        kfA[kb][0] = ks8[(kb * 2 + 0) * 64 + lane];
        kfA[kb][1] = ks8[(kb * 2 + 1) * 64 + lane];
    }

    auto step = [&](int kt, uint2 (&cur)[4][2], uint2 (&nxt)[4][2]) {
        // V fp8 frags issued first (consumed at PV, max latency cover)
        uint2 bvr[2][4];
        #pragma unroll
        for (int cb = 0; cb < 4; cb++) {
            bvr[0][cb] = vt8[((long)kt * 8 + cb * 2 + 0) * 64 + lane];
            bvr[1][cb] = vt8[((long)kt * 8 + cb * 2 + 1) * 64 + lane];
        }

        // upconvert K frags (loaded last step, already resident)
        short8 kbf[4][2];
        #pragma unroll
        for (int kb = 0; kb < 4; kb++) {
            kbf[kb][0] = fp8_to_bf16_frag(cur[kb][0]);
            kbf[kb][1] = fp8_to_bf16_frag(cur[kb][1]);
        }

        f32x4 sc[2][4];
        #pragma unroll
        for (int s = 0; s < 2; s++) {
            #pragma unroll
            for (int kb = 0; kb < 4; kb++) {
                f32x4 z = (f32x4){0.f, 0.f, 0.f, 0.f};
                z = __builtin_amdgcn_mfma_f32_16x16x32_bf16(aq[s][0], kbf[kb][0], z, 0, 0, 0);
                z = __builtin_amdgcn_mfma_f32_16x16x32_bf16(aq[s][1], kbf[kb][1], z, 0, 0, 0);
                sc[s][kb] = z;
            }
        }

        // prefetch next kt's K fp8 frags (flies under exp + PV)
        {
            int ktn = (kt + 1) & 15;
            #pragma unroll
            for (int kb = 0; kb < 4; kb++) {
                nxt[kb][0] = ks8[((long)ktn * 8 + kb * 2 + 0) * 64 + lane];
                nxt[kb][1] = ks8[((long)ktn * 8 + kb * 2 + 1) * 64 + lane];
            }
        }

        #pragma unroll
        for (int s = 0; s < 2; s++) {
            #pragma unroll
            for (int r = 0; r < 4; r++) {
                float p0 = __builtin_amdgcn_exp2f(sc[s][0][r]);
                float p1 = __builtin_amdgcn_exp2f(sc[s][1][r]);
                float p2 = __builtin_amdgcn_exp2f(sc[s][2][r]);
                float p3 = __builtin_amdgcn_exp2f(sc[s][3][r]);
                lsum[s][r] += (p0 + p1) + (p2 + p3);
                *(uint2*)&Pl[wave][s * 16 + quad * 4 + r][l16 * 4] =
                    make_uint2(pack_bf16rn(p0, p1), pack_bf16rn(p2, p3));
            }
        }

        // upconvert V frags (arrived by now), then PV
        short8 bvb[2][4];
        #pragma unroll
        for (int ck = 0; ck < 2; ck++)
            #pragma unroll
            for (int cb = 0; cb < 4; cb++)
                bvb[ck][cb] = fp8_to_bf16_frag(bvr[ck][cb]);

        #pragma unroll
        for (int ck = 0; ck < 2; ck++) {
            #pragma unroll
            for (int s = 0; s < 2; s++) {
                short8 ap = *(const short8*)&Pl[wave][s * 16 + l16][ck * 32 + quad * 8];
                #pragma unroll
                for (int cb = 0; cb < 4; cb++) {
                    O[s][cb] = __builtin_amdgcn_mfma_f32_16x16x32_bf16(ap, bvb[ck][cb], O[s][cb], 0, 0, 0);
                }
            }
        }
    };

    for (int kt = 0; kt < 16; kt += 2) {
        step(kt,     kfA, kfB);
        step(kt + 1, kfB, kfA);
    }

    #pragma unroll
    for (int s = 0; s < 2; s++)
        #pragma unroll
        for (int r = 0; r < 4; r++)
            #pragma unroll
            for (int off = 1; off < 16; off <<= 1)
                lsum[s][r] += __shfl_xor(lsum[s][r], off);

    // epilogue: per-strip f32 transpose via this wave's Pl slab -> vec stores
    float* fst = (float*)&Pl[wave][0][0];    // 4608 B >= 16*68*4 = 4352
    #pragma unroll
    for (int s = 0; s < 2; s++) {
        #pragma unroll
        for (int r = 0; r < 4; r++) {
            float rl = 1.0f / lsum[s][r];
            #pragma unroll
            for (int cb = 0; cb < 4; cb++)
                fst[(quad * 4 + r) * 68 + cb * 16 + l16] = O[s][cb][r] * rl;
        }
        #pragma unroll
        for (int j = 0; j < 4; j++) {
            int vidx = j * 64 + lane;
            int row = vidx >> 4, dp = (vidx & 15) * 4;
            f32x4 ov = *(const f32x4*)&fst[row * 68 + dp];
            long nrow = (long)b * Nsz + qbase + s * 16 + row;
            uint2 qv = *(const uint2*)(qs + nrow * Dsz + dp);
            ov[0] += bf2f((unsigned short)(qv.x)) * INV_SC;
            ov[1] += bf2f((unsigned short)(qv.x >> 16)) * INV_SC;
            ov[2] += bf2f((unsigned short)(qv.y)) * INV_SC;
            ov[3] += bf2f((unsigned short)(qv.y >> 16)) * INV_SC;
            *(f32x4*)(out + nrow * Dsz + dp) = ov;
        }
    }
}

extern "C" void kernel_launch(void* const* d_in, const int* in_sizes, int n_in,
                              void* d_out, int out_size, void* d_ws, size_t ws_size,
                              hipStream_t stream) {
    const float* x  = (const float*)d_in[0];
    const float* Wq = (const float*)d_in[1];
    const float* bq = (const float*)d_in[2];
    const float* Wk = (const float*)d_in[3];
    const float* bk = (const float*)d_in[4];
    const float* Wv = (const float*)d_in[5];
    const float* bv = (const float*)d_in[6];
    float* out = (float*)d_out;

    char* ws = (char*)d_ws;
    unsigned short* qsc   = (unsigned short*)ws;                 // 8 MB bf16 q*SC, [n][d]
    unsigned int*   ks2   = (unsigned int*)(ws + 0x1000000);     // 4 MB fp8 K frag-major
    unsigned int*   vt2   = (unsigned int*)(ws + 0x2000000);     // 4 MB fp8 V frag-major
    unsigned short* wfrag = (unsigned short*)(ws + 0x3000000);   // 48 KB W frags

    wprep_kernel<<<dim3(4), dim3(256), 0, stream>>>(Wq, Wk, Wv, wfrag);
    qkv_kernel<<<dim3(1024), dim3(256), 0, stream>>>(
        x, wfrag, bq, bk, bv, qsc, ks2, vt2);
    attn_kernel<<<dim3(512), dim3(256), 0, stream>>>(
        qsc, ks2, vt2, out);
}

// Round 10
// 135.176 us; speedup vs baseline: 1.0286x; 1.0286x over previous
//
#include <hip/hip_runtime.h>
#include <hip/hip_bf16.h>

// SelfAttentionLayer: B=64, N=1024, C=128, D=64
// R9: P LDS round-trip eliminated. QK computed as S^T (operands swapped:
// mfma(K_frag, Q_frag)) so the score C-layout (q=l16, key=quad*4+r) IS the
// B-fragment layout of mfma_f32_16x16x16_bf16. exp2 in-register, pack, and
// PV consumes P directly: O^T += V^T_frag * P. attn K-loop: no LDS, no
// barriers, no shuffles. V stored by qkv in the 16x16x16 A-frag image.
// K/V revert to bf16 (R8's fp8 upconvert made VALU the bottleneck: 51%).

#define Bsz 64
#define Nsz 1024
#define Csz 128
#define Dsz 64

typedef __attribute__((ext_vector_type(8))) short short8;
typedef __attribute__((ext_vector_type(4))) short short4v;
typedef __attribute__((ext_vector_type(4))) float f32x4;

__device__ __forceinline__ unsigned short f2bf(float f) {
    union { float f; unsigned u; } v; v.f = f;
    unsigned r = v.u + 0x7FFF + ((v.u >> 16) & 1);
    return (unsigned short)(r >> 16);
}
__device__ __forceinline__ float bf2f(unsigned short h) {
    union { unsigned u; float f; } v; v.u = ((unsigned)h) << 16;
    return v.f;
}
// pack two fp32 -> bf16x2 dword (round-nearest ties-up)
__device__ __forceinline__ unsigned pack_bf16rn(float lo, float hi) {
    unsigned ulo = __float_as_uint(lo) + 0x8000u;
    unsigned uhi = __float_as_uint(hi) + 0x8000u;
    return __builtin_amdgcn_perm(uhi, ulo, 0x07060302u);
}
// 16x16x16 bf16 MFMA (K=16): builtin if present, else raw asm (ISA-listed)
__device__ __forceinline__ f32x4 mfma_16x16x16_bf16(short4v a, short4v b, f32x4 c) {
#if __has_builtin(__builtin_amdgcn_mfma_f32_16x16x16bf16_1k)
    return __builtin_amdgcn_mfma_f32_16x16x16bf16_1k(a, b, c, 0, 0, 0);
#else
    asm volatile("v_mfma_f32_16x16x16_bf16 %0, %1, %2, %0"
                 : "+v"(c) : "v"(a), "v"(b));
    return c;
#endif
}

#define SCq (0.125f * 1.44269504f)     // 1/sqrt(D) * log2(e) folded into qs
#define INV_SC (1.0f / (0.125f * 1.44269504f))

// ---------------- Kernel 0: weight prep -> B-frag layout bf16 ----------------
__global__ __launch_bounds__(256) void wprep_kernel(
    const float* __restrict__ Wq, const float* __restrict__ Wk,
    const float* __restrict__ Wv, unsigned short* __restrict__ wfrag)
{
    int t = blockIdx.x * 256 + threadIdx.x;   // 0..1023 = (dt,ksi,lane)
    int lane = t & 63, ksi = (t >> 6) & 3, dt = t >> 8;
    int l16 = lane & 15, quad = lane >> 4;
    int d = dt * 16 + l16;
    int c0 = ksi * 32 + quad * 8;
    short8 q8, k8, v8;
    #pragma unroll
    for (int j = 0; j < 8; j++) {
        q8[j] = (short)f2bf(Wq[(c0 + j) * Dsz + d]);
        k8[j] = (short)f2bf(Wk[(c0 + j) * Dsz + d]);
        v8[j] = (short)f2bf(Wv[(c0 + j) * Dsz + d]);
    }
    int idx = (dt * 4 + ksi) * 64 + lane;
    ((short8*)wfrag)[0 * 1024 + idx] = q8;
    ((short8*)wfrag)[1 * 1024 + idx] = k8;
    ((short8*)wfrag)[2 * 1024 + idx] = v8;
}

// ---------------- Kernel A: QKV projection via MFMA ----------------
// grid 1024 x 256; block = 64 rows; wave = d-tile dt.
// ks2: K frag-major (16x16x32 layout). vt2: V in 16x16x16 A-frag image:
//   frag(kb,cb): lane l (l16=d-in-block, quad), elems i: V[kt*64+kb*16+quad*4+i][cb*16+l16]
__global__ __launch_bounds__(256) void qkv_kernel(
    const float* __restrict__ x, const unsigned short* __restrict__ wfrag,
    const float* __restrict__ bq, const float* __restrict__ bk,
    const float* __restrict__ bv,
    unsigned short* __restrict__ qs, unsigned short* __restrict__ ks2,
    unsigned short* __restrict__ vt2)
{
    __shared__ short lds[16384];          // 32 KB: xh (16 KB) | transpose bufs
    short* xh = lds;
    const int t    = threadIdx.x;
    const int lane = t & 63;
    const int l16  = lane & 15, quad = lane >> 4;
    const int dt   = t >> 6;
    const long rowbase = (long)blockIdx.x * 64;
    const int d = dt * 16 + l16;

    // weight B-frags: 12 coalesced b128 loads (L2-hot wfrag)
    short8 wqf[4], wkf[4], wvf[4];
    #pragma unroll
    for (int ksi = 0; ksi < 4; ksi++) {
        int idx = (dt * 4 + ksi) * 64 + lane;
        wqf[ksi] = ((const short8*)wfrag)[0 * 1024 + idx];
        wkf[ksi] = ((const short8*)wfrag)[1 * 1024 + idx];
        wvf[ksi] = ((const short8*)wfrag)[2 * 1024 + idx];
    }

    // stage x -> bf16 in A-frag layout (v_perm packs)
    {
        const int row = t & 63;
        const float* xrow = x + (rowbase + row) * Csz;
        #pragma unroll
        for (int p = 0; p < 4; p++) {
            int cb = (t >> 6) + p * 4;
            float4 a  = *(const float4*)(xrow + cb * 8);
            float4 bb = *(const float4*)(xrow + cb * 8 + 4);
            uint4 hi4;
            hi4.x = pack_bf16rn(a.x,  a.y);
            hi4.y = pack_bf16rn(a.z,  a.w);
            hi4.z = pack_bf16rn(bb.x, bb.y);
            hi4.w = pack_bf16rn(bb.z, bb.w);
            int unit = ((row >> 4) * 4 + (cb >> 2)) * 64 + ((row & 15) | ((cb & 3) << 4));
            *(uint4*)&xh[unit * 8] = hi4;
        }
    }
    __syncthreads();

    f32x4 aq[4], ak[4], av[4];
    #pragma unroll
    for (int i = 0; i < 4; i++) {
        aq[i] = (f32x4){0.f, 0.f, 0.f, 0.f};
        ak[i] = (f32x4){0.f, 0.f, 0.f, 0.f};
        av[i] = (f32x4){0.f, 0.f, 0.f, 0.f};
    }
    #pragma unroll
    for (int ksi = 0; ksi < 4; ksi++) {
        #pragma unroll
        for (int rt = 0; rt < 4; rt++) {
            short8 ah = *(const short8*)&xh[((rt * 4 + ksi) * 64 + lane) * 8];
            aq[rt] = __builtin_amdgcn_mfma_f32_16x16x32_bf16(ah, wqf[ksi], aq[rt], 0, 0, 0);
            ak[rt] = __builtin_amdgcn_mfma_f32_16x16x32_bf16(ah, wkf[ksi], ak[rt], 0, 0, 0);
            av[rt] = __builtin_amdgcn_mfma_f32_16x16x32_bf16(ah, wvf[ksi], av[rt], 0, 0, 0);
        }
    }

    // ---- epilogue: bias+relu -> LDS -> coalesced stores ----
    const float bqd = bq[d], bkd = bk[d], bvd = bv[d];
    const long b  = rowbase >> 10;
    const int  kt = (int)((rowbase >> 6) & 15);

    __syncthreads();                      // xh reads all done; reuse buffer
    short* stq = lds;                     // [64][72] bf16
    short* stk = lds + 4608;              // [64][72] bf16
    short* stv = lds + 9216;              // [16 frag][64 lane][4] bf16

    float vv[4][4];
    #pragma unroll
    for (int rt = 0; rt < 4; rt++) {
        #pragma unroll
        for (int r = 0; r < 4; r++) {
            int nl = rt * 16 + quad * 4 + r;
            float q = fmaxf(aq[rt][r] + bqd, 0.f);
            float k = fmaxf(ak[rt][r] + bkd, 0.f);
            vv[r][rt] = fmaxf(av[rt][r] + bvd, 0.f);
            stq[nl * 72 + d] = (short)f2bf(q * SCq);
            stk[nl * 72 + d] = (short)f2bf(k);
        }
    }
    // V frag image: frag (kb=rt, cb=dt), this lane, elems i=r
    #pragma unroll
    for (int rt = 0; rt < 4; rt++) {
        uint2 pk = make_uint2(pack_bf16rn(vv[0][rt], vv[1][rt]),
                              pack_bf16rn(vv[2][rt], vv[3][rt]));
        *(uint2*)&stv[((rt * 4 + dt) * 64 + lane) * 4] = pk;
    }
    __syncthreads();

    const long tbase = (long)(b * 16 + kt) * 512;
    #pragma unroll
    for (int i = 0; i < 2; i++) {
        int sidx = i * 256 + t;
        // qs [n][d]: fully coalesced b128
        int row = sidx >> 3, g = sidx & 7;
        short8 vq = *(const short8*)&stq[row * 72 + g * 8];
        ((short8*)qs)[(rowbase + row) * 8 + g] = vq;
        // K frag-major b128
        int kb = sidx >> 7, rem = sidx & 127, half = rem >> 6, lam = rem & 63;
        short8 vk = *(const short8*)&stk[(kb * 16 + (lam & 15)) * 72 + half * 32 + (lam >> 4) * 8];
        ((short8*)ks2)[tbase + kb * 128 + half * 64 + lam] = vk;
        // V frag image b128 (already ordered)
        ((uint4*)vt2)[tbase + sidx] = *(const uint4*)&stv[sidx * 8];
    }
}

// ---------------- Kernel B: LDS-free flash attention ----------------
// grid 512 x 256: b = blk&63 (XCD affinity), qh = blk>>6. 4 waves x 32 q.
// S^T via mfma(K,Q); P fed straight into 16x16x16 PV as B-operand.
__global__ __launch_bounds__(256) void attn_kernel(
    const unsigned short* __restrict__ qs,
    const unsigned short* __restrict__ ks2,
    const unsigned short* __restrict__ vt2,
    float* __restrict__ out)
{
    const int t    = threadIdx.x;
    const int wave = t >> 6;
    const int lane = t & 63;
    const int l16  = lane & 15;
    const int quad = lane >> 4;
    const int b    = blockIdx.x & 63;
    const int qh   = blockIdx.x >> 6;
    const int qbase = qh * 128 + wave * 32;

    const short8* ks8 = (const short8*)ks2 + (long)b * 8192;
    const uint2*  vt8 = (const uint2*)vt2 + (long)b * 16384;

    // Q B-frags (2 strips of 16 q)
    short8 aq[2][2];
    #pragma unroll
    for (int s = 0; s < 2; s++) {
        const unsigned short* qp = qs + ((long)b * Nsz + qbase + s * 16 + l16) * Dsz + quad * 8;
        aq[s][0] = *(const short8*)(qp);
        aq[s][1] = *(const short8*)(qp + 32);
    }

    // O^T accumulators: O[s][cb][r] = O^T[d=cb*16+quad*4+r][q=l16 (strip s)]
    f32x4 O[2][4];
    float lsum[2] = {0.f, 0.f};
    #pragma unroll
    for (int s = 0; s < 2; s++)
        #pragma unroll
        for (int i = 0; i < 4; i++) O[s][i] = (f32x4){0.f, 0.f, 0.f, 0.f};

    short8 kfA[4][2], kfB[4][2];
    #pragma unroll
    for (int kb = 0; kb < 4; kb++) {
        kfA[kb][0] = ks8[(kb * 2 + 0) * 64 + lane];
        kfA[kb][1] = ks8[(kb * 2 + 1) * 64 + lane];
    }

    auto step = [&](int kt, short8 (&cur)[4][2], short8 (&nxt)[4][2]) {
        // V A-frags for this kt (16 x b64, consumed at PV)
        uint2 vr[4][4];
        #pragma unroll
        for (int kb = 0; kb < 4; kb++)
            #pragma unroll
            for (int cb = 0; cb < 4; cb++)
                vr[kb][cb] = vt8[(long)kt * 1024 + (kb * 4 + cb) * 64 + lane];

        // S^T = K Q^T per strip: lane holds q=l16, keys kb*16+quad*4+r
        f32x4 sc[2][4];
        #pragma unroll
        for (int s = 0; s < 2; s++) {
            #pragma unroll
            for (int kb = 0; kb < 4; kb++) {
                f32x4 z = (f32x4){0.f, 0.f, 0.f, 0.f};
                z = __builtin_amdgcn_mfma_f32_16x16x32_bf16(cur[kb][0], aq[s][0], z, 0, 0, 0);
                z = __builtin_amdgcn_mfma_f32_16x16x32_bf16(cur[kb][1], aq[s][1], z, 0, 0, 0);
                sc[s][kb] = z;
            }
        }

        // prefetch next kt's K frags (cur fully consumed)
        {
            int ktn = (kt + 1) & 15;
            #pragma unroll
            for (int kb = 0; kb < 4; kb++) {
                nxt[kb][0] = ks8[((long)ktn * 8 + kb * 2 + 0) * 64 + lane];
                nxt[kb][1] = ks8[((long)ktn * 8 + kb * 2 + 1) * 64 + lane];
            }
        }

        // P = 2^S in-register -> straight into PV as B-operand (no LDS!)
        #pragma unroll
        for (int s = 0; s < 2; s++) {
            #pragma unroll
            for (int kb = 0; kb < 4; kb++) {
                float p0 = __builtin_amdgcn_exp2f(sc[s][kb][0]);
                float p1 = __builtin_amdgcn_exp2f(sc[s][kb][1]);
                float p2 = __builtin_amdgcn_exp2f(sc[s][kb][2]);
                float p3 = __builtin_amdgcn_exp2f(sc[s][kb][3]);
                lsum[s] += (p0 + p1) + (p2 + p3);
                union { uint2 u; short4v s4; } bp;
                bp.u = make_uint2(pack_bf16rn(p0, p1), pack_bf16rn(p2, p3));
                #pragma unroll
                for (int cb = 0; cb < 4; cb++) {
                    union { uint2 u; short4v s4; } va; va.u = vr[kb][cb];
                    O[s][cb] = mfma_16x16x16_bf16(va.s4, bp.s4, O[s][cb]);
                }
            }
        }
    };

    for (int kt = 0; kt < 16; kt += 2) {
        step(kt,     kfA, kfB);
        step(kt + 1, kfB, kfA);
    }

    // lsum: lane already summed its 16 keys/kt; combine the 4 quads per q
    #pragma unroll
    for (int s = 0; s < 2; s++) {
        lsum[s] += __shfl_xor(lsum[s], 16);
        lsum[s] += __shfl_xor(lsum[s], 32);
    }

    // epilogue: lane owns q=l16 (strip s), d = cb*16+quad*4+(0..3) contiguous
    #pragma unroll
    for (int s = 0; s < 2; s++) {
        float rl = 1.0f / lsum[s];
        long nrow = (long)b * Nsz + qbase + s * 16 + l16;
        #pragma unroll
        for (int cb = 0; cb < 4; cb++) {
            int d0 = cb * 16 + quad * 4;
            uint2 qv = *(const uint2*)(qs + nrow * Dsz + d0);
            f32x4 ov;
            ov[0] = O[s][cb][0] * rl + bf2f((unsigned short)(qv.x)) * INV_SC;
            ov[1] = O[s][cb][1] * rl + bf2f((unsigned short)(qv.x >> 16)) * INV_SC;
            ov[2] = O[s][cb][2] * rl + bf2f((unsigned short)(qv.y)) * INV_SC;
            ov[3] = O[s][cb][3] * rl + bf2f((unsigned short)(qv.y >> 16)) * INV_SC;
            *(f32x4*)(out + nrow * Dsz + d0) = ov;
        }
    }
}

extern "C" void kernel_launch(void* const* d_in, const int* in_sizes, int n_in,
                              void* d_out, int out_size, void* d_ws, size_t ws_size,
                              hipStream_t stream) {
    const float* x  = (const float*)d_in[0];
    const float* Wq = (const float*)d_in[1];
    const float* bq = (const float*)d_in[2];
    const float* Wk = (const float*)d_in[3];
    const float* bk = (const float*)d_in[4];
    const float* Wv = (const float*)d_in[5];
    const float* bv = (const float*)d_in[6];
    float* out = (float*)d_out;

    char* ws = (char*)d_ws;
    unsigned short* qsc   = (unsigned short*)ws;                 // 8 MB bf16 q*SC, [n][d]
    unsigned short* ks2   = (unsigned short*)(ws + 0x1000000);   // 8 MB bf16 K frag-major
    unsigned short* vt2   = (unsigned short*)(ws + 0x2000000);   // 8 MB bf16 V 16x16x16-A image
    unsigned short* wfrag = (unsigned short*)(ws + 0x3000000);   // 48 KB W frags

    wprep_kernel<<<dim3(4), dim3(256), 0, stream>>>(Wq, Wk, Wv, wfrag);
    qkv_kernel<<<dim3(1024), dim3(256), 0, stream>>>(
        x, wfrag, bq, bk, bv, qsc, ks2, vt2);
    attn_kernel<<<dim3(512), dim3(256), 0, stream>>>(
        qsc, ks2, vt2, out);
}